// Round 1
// baseline (127.100 us; speedup 1.0000x reference)
//
#include <hip/hip_runtime.h>

// NormalizedCutLoss on MI355X.
// P = 64*64 = 4096 pixels/image after 0.5x resize; features: 3 rgb/15 + 2 xy/40.
// num = sum_{i,j} exp(-0.5*max(d2,0)) * dot21(S_i,S_j); den = sum_{i,j} w_ij * stot_i.
// out = -(sum num)/(sum den)/N.

#define NIMG 8
#define KSEG 21
#define HO 64
#define WO 64
#define PIX 4096      // HO*WO
#define HI 128
#define WI 128
#define C_PIX 28      // f0..f4, sq, stot, S0..S20

#define THREADS 256
#define JPT 4
#define TJ (THREADS * JPT)     // 1024
#define NJT (PIX / TJ)         // 4
#define ISPLIT 16
#define ILEN (PIX / ISPLIT)    // 256
#define ICH 128
#define NCH (ILEN / ICH)       // 2

__global__ void prep_kernel(const float* __restrict__ images,
                            const float* __restrict__ segs,
                            const float* __restrict__ rois,
                            float* __restrict__ feat,   // [NIMG][PIX][C_PIX]
                            double* __restrict__ acc) {
    int idx = blockIdx.x * blockDim.x + threadIdx.x;
    if (idx == 0) { acc[0] = 0.0; acc[1] = 0.0; }
    if (idx >= NIMG * PIX) return;
    int n = idx / PIX, p = idx % PIX;
    int y = p / WO, x = p % WO;
    int yi = 2 * y, xi = 2 * x;

    const float INV_SRGB = 1.0f / 15.0f;
    const float INV_SXY  = 1.0f / 40.0f;   // 1/(SIGMA_XY*SCALE)

    const float* im = images + (size_t)n * 3 * HI * WI;
    float r = im[0 * HI * WI + yi * WI + xi] * INV_SRGB;
    float g = im[1 * HI * WI + yi * WI + xi] * INV_SRGB;
    float b = im[2 * HI * WI + yi * WI + xi] * INV_SRGB;
    float fx = (float)x * INV_SXY;
    float fy = (float)y * INV_SXY;
    float sq = r * r + g * g + b * b + fx * fx + fy * fy;
    float roi = rois[(size_t)n * HI * WI + yi * WI + xi];

    float* o = feat + (size_t)idx * C_PIX;
    o[0] = r; o[1] = g; o[2] = b; o[3] = fx; o[4] = fy; o[5] = sq;

    float stot = 0.0f;
    const float* sg = segs + (size_t)n * KSEG * HI * WI;
    #pragma unroll
    for (int k = 0; k < KSEG; ++k) {
        const float* s2 = sg + (size_t)k * HI * WI + yi * WI + xi;
        float v = 0.25f * (s2[0] + s2[1] + s2[WI] + s2[WI + 1]) * roi;
        o[7 + k] = v;
        stot += v;
    }
    o[6] = stot;
}

__global__ __launch_bounds__(THREADS)
void pair_kernel(const float* __restrict__ feat, double* __restrict__ acc) {
    __shared__ float lds[ICH * C_PIX];
    __shared__ float red[2][THREADS / 64];

    int b = blockIdx.x;
    int n   = b / (NJT * ISPLIT);
    int rem = b % (NJT * ISPLIT);
    int jt  = rem / ISPLIT;
    int isp = rem % ISPLIT;
    const float* fimg = feat + (size_t)n * PIX * C_PIX;
    int tid = threadIdx.x;

    // Load this thread's JPT j-pixels into registers (28 floats each, 16B-aligned).
    float fj[JPT][5], sqj[JPT], Sj[JPT][KSEG];
    int j0 = jt * TJ + tid * JPT;
    #pragma unroll
    for (int jj = 0; jj < JPT; ++jj) {
        float tmp[C_PIX];
        const float4* src = reinterpret_cast<const float4*>(fimg + (size_t)(j0 + jj) * C_PIX);
        #pragma unroll
        for (int q = 0; q < 7; ++q) reinterpret_cast<float4*>(tmp)[q] = src[q];
        #pragma unroll
        for (int c = 0; c < 5; ++c) fj[jj][c] = tmp[c];
        sqj[jj] = tmp[5];
        #pragma unroll
        for (int k = 0; k < KSEG; ++k) Sj[jj][k] = tmp[7 + k];
    }

    float num = 0.0f, den = 0.0f;

    for (int ic = 0; ic < NCH; ++ic) {
        int i0 = isp * ILEN + ic * ICH;
        __syncthreads();
        // Coalesced contiguous copy of the i-chunk (128 pixels * 28 floats).
        for (int idx = tid; idx < ICH * C_PIX; idx += THREADS)
            lds[idx] = fimg[(size_t)i0 * C_PIX + idx];
        __syncthreads();

        for (int ii = 0; ii < ICH; ++ii) {
            const float* li = lds + ii * C_PIX;   // wave-uniform address: broadcast reads
            float fi0 = li[0], fi1 = li[1], fi2 = li[2], fi3 = li[3], fi4 = li[4];
            float sqi = li[5], stoti = li[6];
            #pragma unroll
            for (int jj = 0; jj < JPT; ++jj) {
                float dot = fi0 * fj[jj][0];
                dot = fmaf(fi1, fj[jj][1], dot);
                dot = fmaf(fi2, fj[jj][2], dot);
                dot = fmaf(fi3, fj[jj][3], dot);
                dot = fmaf(fi4, fj[jj][4], dot);
                float d2 = fmaf(-2.0f, dot, sqi + sqj[jj]);
                d2 = fmaxf(d2, 0.0f);
                float w = __expf(-0.5f * d2);
                float gsum = li[7] * Sj[jj][0];
                #pragma unroll
                for (int k = 1; k < KSEG; ++k) gsum = fmaf(li[7 + k], Sj[jj][k], gsum);
                num = fmaf(w, gsum, num);
                den = fmaf(w, stoti, den);
            }
        }
    }

    // Wave reduce then block reduce, one double atomic per block.
    #pragma unroll
    for (int off = 32; off > 0; off >>= 1) {
        num += __shfl_down(num, off);
        den += __shfl_down(den, off);
    }
    int wid = tid >> 6, lane = tid & 63;
    if (lane == 0) { red[0][wid] = num; red[1][wid] = den; }
    __syncthreads();
    if (tid == 0) {
        float n4 = 0.0f, d4 = 0.0f;
        #pragma unroll
        for (int w = 0; w < THREADS / 64; ++w) { n4 += red[0][w]; d4 += red[1][w]; }
        atomicAdd(&acc[0], (double)n4);
        atomicAdd(&acc[1], (double)d4);
    }
}

__global__ void final_kernel(const double* __restrict__ acc, float* __restrict__ out) {
    out[0] = (float)(-(acc[0] / acc[1]) / (double)NIMG);
}

extern "C" void kernel_launch(void* const* d_in, const int* in_sizes, int n_in,
                              void* d_out, int out_size, void* d_ws, size_t ws_size,
                              hipStream_t stream) {
    const float* images = (const float*)d_in[0];
    const float* segs   = (const float*)d_in[1];
    const float* rois   = (const float*)d_in[2];
    float* out = (float*)d_out;

    double* acc = (double*)d_ws;
    float* feat = (float*)((char*)d_ws + 256);   // 3.67 MB needed

    prep_kernel<<<(NIMG * PIX + 255) / 256, 256, 0, stream>>>(images, segs, rois, feat, acc);
    pair_kernel<<<NIMG * NJT * ISPLIT, THREADS, 0, stream>>>(feat, acc);
    final_kernel<<<1, 1, 0, stream>>>(acc, out);
}